// Round 4
// baseline (105.140 us; speedup 1.0000x reference)
//
#include <hip/hip_runtime.h>

#define BB 8
#define HH 256
#define LL 4096
#define STR 72          // LDS row stride in shorts (144 B: 16B-aligned rows, even bank spread)

// ws byte offsets (ws ~234 MB; we use ~6.2 MB, fully rewritten every call)
#define WS_H  0
#define WS_P  (2u*1024*1024)
#define WS_R  (4u*1024*1024)
#define WS_C1 (6u*1024*1024)
#define WS_C2 (6u*1024*1024 + 128u*1024)

typedef __attribute__((ext_vector_type(8))) short short8;   // 8 bf16 = MFMA A/B frag
typedef __attribute__((ext_vector_type(4))) float f32x4;    // MFMA C/D frag

static __device__ inline unsigned short f2bf(float x) {
    union { float f; unsigned u; } v; v.f = x;
    unsigned r = v.u + 0x7fffu + ((v.u >> 16) & 1u);   // RNE
    return (unsigned short)(r >> 16);
}
static __device__ inline float bf2f(unsigned short us) {
    union { unsigned u; float f; } v; v.u = ((unsigned)us) << 16; return v.f;
}

#define CMUL(or_, oi_, ar_, ai_, br_, bi_) do { \
    float _tr = fmaf((ar_), (br_), -(ai_) * (bi_)); \
    float _ti = fmaf((ar_), (bi_), (ai_) * (br_)); \
    (or_) = _tr; (oi_) = _ti; } while (0)

// ---------------- Precompute: one block per h (256 blocks x 256 threads) ----
// Builds Hmat[t][tau] (Toeplitz of h), Pmat[dd][tau] (powers for chunk end
// states), Rmat[k][dd] (correction matrix), all bf16 64x64 row-major, plus
// per-(h,d) f32 constants: C1 = (Ar, Ai, wr_r, wr_i), C2 = v.
__global__ __launch_bounds__(256) void s4_pre_kernel(
    const float* __restrict__ theta, const float* __restrict__ a,
    const float* __restrict__ b_p,   const float* __restrict__ c_p,
    const float* __restrict__ x0,
    unsigned short* __restrict__ Hm, unsigned short* __restrict__ Pm,
    unsigned short* __restrict__ Rm, float4* __restrict__ C1,
    float* __restrict__ C2)
{
    const int tid = threadIdx.x;
    const int h   = blockIdx.x;
    const int d   = tid & 31;
    const int kb  = tid >> 5;
    const float T = 1.0f / (LL - 1);
    __shared__ float h_s[64];

    const float lr = a[h * 32 + d];
    const float li = theta[h * 32 + d];
    float sn, cS;
    sincosf(li * T, &sn, &cS);
    const float er = expf(lr * T);
    const float Rr = er * cS, Ri = er * sn;      // r = exp(ls*T)
    const float den = lr * lr + li * li;
    const float t0r = ((Rr - 1.f) * lr + Ri * li) / den;
    const float t0i = (Ri * lr - (Rr - 1.f) * li) / den;
    const float qq  = b_p[h * 32 + d] * c_p[h * 32 + d];
    const float wre = 2.f * qq * t0r, wim = 2.f * qq * t0i;
    const float vv  = 4.f * T * c_p[h * 32 + d] * x0[h * 32 + d];

    float r2r, r2i, r4r, r4i, r8r, r8i, r16r, r16i, r32r, r32i;
    CMUL(r2r, r2i, Rr, Ri, Rr, Ri);
    CMUL(r4r, r4i, r2r, r2i, r2r, r2i);
    CMUL(r8r, r8i, r4r, r4i, r4r, r4i);
    CMUL(r16r, r16i, r8r, r8i, r8r, r8i);
    CMUL(r32r, r32i, r16r, r16i, r16r, r16i);

    unsigned short* HmB = Hm + h * 4096;
    unsigned short* PmB = Pm + h * 4096;
    unsigned short* RmB = Rm + h * 4096;

    {   // powers r^(8kb)..: fill Rmat, Pmat, reduce h_k
        float pr = 1.f, pi = 0.f;
        if (kb & 1) CMUL(pr, pi, pr, pi, r8r, r8i);
        if (kb & 2) CMUL(pr, pi, pr, pi, r16r, r16i);
        if (kb & 4) CMUL(pr, pi, pr, pi, r32r, r32i);
        #pragma unroll
        for (int k8 = 0; k8 < 8; ++k8) {
            const int k = (kb << 3) + k8;
            RmB[k * 64 + d]           = f2bf(pr);
            RmB[k * 64 + 32 + d]      = f2bf(-pi);
            PmB[d * 64 + (63 - k)]        = f2bf(pr);
            PmB[(32 + d) * 64 + (63 - k)] = f2bf(pi);
            float hk = fmaf(wre, pr, -wim * pi);     // Re(w * r^k)
            hk += __shfl_xor(hk, 1);
            hk += __shfl_xor(hk, 2);
            hk += __shfl_xor(hk, 4);
            hk += __shfl_xor(hk, 8);
            hk += __shfl_xor(hk, 16);
            if (d == 0) h_s[k] = hk;
            CMUL(pr, pi, pr, pi, Rr, Ri);
        }
    }
    if (tid < 32) {
        float Ar, Ai, wrr, wri;
        CMUL(Ar, Ai, r32r, r32i, r32r, r32i);        // A = r^64
        CMUL(wrr, wri, wre, wim, Rr, Ri);            // w*r
        C1[h * 32 + d] = make_float4(Ar, Ai, wrr, wri);
        C2[h * 32 + d] = vv;
    }
    __syncthreads();

    // Toeplitz Hmat[t][tau] = h[t-tau]
    {
        const int t  = tid >> 2;
        const int tb = (tid & 3) << 4;
        #pragma unroll
        for (int g = 0; g < 4; ++g) {
            const int tau0 = tb + (g << 2);
            unsigned short e[4];
            #pragma unroll
            for (int i = 0; i < 4; ++i) {
                const int dt = t - (tau0 + i);
                e[i] = (dt >= 0) ? f2bf(h_s[dt]) : (unsigned short)0;
            }
            uint2 pk;
            pk.x = (unsigned)e[0] | ((unsigned)e[1] << 16);
            pk.y = (unsigned)e[2] | ((unsigned)e[3] << 16);
            *(uint2*)&HmB[t * 64 + tau0] = pk;
        }
    }
}

// ---------------- Main: one block per (b,h) ----------------
__global__ __launch_bounds__(256, 5) void s4_main_kernel(
    const float* __restrict__ u, const float* __restrict__ Dp,
    const unsigned short* __restrict__ Hm, const unsigned short* __restrict__ Pm,
    const unsigned short* __restrict__ Rm, const float4* __restrict__ C1,
    const float* __restrict__ C2, float* __restrict__ out)
{
    const int tid = threadIdx.x;
    const int bh  = blockIdx.x;
    const int hh  = bh & (HH - 1);

    __shared__ __align__(16) short Us[64 * STR];   // u bf16 [c][tau], lives whole kernel
    __shared__ __align__(16) short EQ[64 * STR];   // E planar [c][dd] -> later Q [c][dd]
    __shared__ __align__(16) float Seg[32 * 18];   // per-d segment sums (complex)

    // ---- stage u -> Us (bf16) ----
    const float* up = u + ((size_t)bh << 12);
    #pragma unroll
    for (int jj = 0; jj < 4; ++jj) {
        const int v  = tid + (jj << 8);
        const float4 val = ((const float4*)up)[v];
        const int c  = v >> 4;
        const int t0 = (v & 15) << 2;
        uint2 pk;
        pk.x = (unsigned)f2bf(val.x) | ((unsigned)f2bf(val.y) << 16);
        pk.y = (unsigned)f2bf(val.z) | ((unsigned)f2bf(val.w) << 16);
        *(uint2*)&Us[c * STR + t0] = pk;
    }

    // ---- per-thread constants (from ws) ----
    const int d = tid & 31;
    const int g = tid >> 5;                         // scan segment 0..7
    const float4 c1 = C1[hh * 32 + d];              // Ar, Ai, wr_r, wr_i
    const float vv  = C2[hh * 32 + d];
    const float Dh  = Dp[hh];
    __syncthreads();                                // b1: Us ready

    // ---- mm1 (Y1 = H x U) + mm2 (E = P x U); A-frags straight from global ----
    const int ln   = tid & 63;
    const int m0   = (tid >> 6) << 4;
    const int rowi = ln & 15;
    const int quad = ln >> 4;
    const unsigned short* HmB = Hm + hh * 4096;
    const unsigned short* PmB = Pm + hh * 4096;
    const unsigned short* RmB = Rm + hh * 4096;
    f32x4 accY[4], accE[4];
    #pragma unroll
    for (int nt = 0; nt < 4; ++nt) {
        accY[nt] = (f32x4){0.f, 0.f, 0.f, 0.f};
        accE[nt] = (f32x4){0.f, 0.f, 0.f, 0.f};
    }
    #pragma unroll
    for (int k0 = 0; k0 < 64; k0 += 32) {
        const short8 aH = *(const short8*)&HmB[(m0 + rowi) * 64 + k0 + (quad << 3)];
        const short8 aP = *(const short8*)&PmB[(m0 + rowi) * 64 + k0 + (quad << 3)];
        #pragma unroll
        for (int nt = 0; nt < 4; ++nt) {
            const short8 bU = *(const short8*)&Us[((nt << 4) + rowi) * STR + k0 + (quad << 3)];
            accY[nt] = __builtin_amdgcn_mfma_f32_16x16x32_bf16(aH, bU, accY[nt], 0, 0, 0);
            accE[nt] = __builtin_amdgcn_mfma_f32_16x16x32_bf16(aP, bU, accE[nt], 0, 0, 0);
        }
    }

    // ---- write E planar: EQ[c][dd], dd = m0 + 4*quad + i, c = 16*nt + rowi ----
    #pragma unroll
    for (int nt = 0; nt < 4; ++nt) {
        uint2 pk;
        pk.x = (unsigned)f2bf(accE[nt][0]) | ((unsigned)f2bf(accE[nt][1]) << 16);
        pk.y = (unsigned)f2bf(accE[nt][2]) | ((unsigned)f2bf(accE[nt][3]) << 16);
        *(uint2*)&EQ[((nt << 4) + rowi) * STR + m0 + (quad << 2)] = pk;
    }
    __syncthreads();                                // b2: E ready

    // ---- scan phase a: thread (d,g) owns chunks 8g..8g+7; E kept in regs ----
    const float Ar = c1.x, Ai = c1.y;
    float Er[8], Ei[8];
    {
        float Sr = 0.f, Si = 0.f;
        #pragma unroll
        for (int i = 0; i < 8; ++i) {
            const int c = (g << 3) + i;
            Er[i] = bf2f((unsigned short)EQ[c * STR + d]);
            Ei[i] = bf2f((unsigned short)EQ[c * STR + 32 + d]);
            const float nr = fmaf(Ar, Sr, fmaf(-Ai, Si, Er[i]));
            const float ni = fmaf(Ar, Si, fmaf(Ai, Sr, Ei[i]));
            Sr = nr; Si = ni;
        }
        Seg[d * 18 + (g << 1)]     = Sr;
        Seg[d * 18 + (g << 1) + 1] = Si;
    }
    __syncthreads();                                // b3: Seg ready

    // ---- scan phase c: combine + emit Q over EQ ----
    {
        float S8r, S8i, S16r, S16i, S32r, S32i;     // A^8, A^16, A^32
        float b1r, b1i, b2r, b2i;
        CMUL(b1r, b1i, Ar, Ai, Ar, Ai);
        CMUL(b2r, b2i, b1r, b1i, b1r, b1i);
        CMUL(S8r, S8i, b2r, b2i, b2r, b2i);
        CMUL(S16r, S16i, S8r, S8i, S8r, S8i);
        CMUL(S32r, S32i, S16r, S16i, S16r, S16i);
        float offr = 0.f, offi = 0.f;
        #pragma unroll
        for (int gp = 0; gp < 7; ++gp) {
            const float2 sg = *(const float2*)&Seg[d * 18 + (gp << 1)];
            const float nr = fmaf(S8r, offr, fmaf(-S8i, offi, sg.x));
            const float ni = fmaf(S8r, offi, fmaf(S8i, offr, sg.y));
            const bool take = gp < g;
            offr = take ? nr : offr;
            offi = take ? ni : offi;
        }
        float Gr = vv, Gi = 0.f;                    // v * A^(8g)
        if (g & 1) { float nr, ni; CMUL(nr, ni, Gr, Gi, S8r, S8i);   Gr = nr; Gi = ni; }
        if (g & 2) { float nr, ni; CMUL(nr, ni, Gr, Gi, S16r, S16i); Gr = nr; Gi = ni; }
        if (g & 4) { float nr, ni; CMUL(nr, ni, Gr, Gi, S32r, S32i); Gr = nr; Gi = ni; }
        const float wrr = c1.z, wri = c1.w;
        float Sr = offr, Si = offi;
        #pragma unroll
        for (int i = 0; i < 8; ++i) {
            const int c = (g << 3) + i;
            const float Qr = fmaf(wrr, Sr, fmaf(-wri, Si, Gr));
            const float Qi = fmaf(wrr, Si, fmaf(wri, Sr, Gi));
            EQ[c * STR + d]      = (short)f2bf(Qr);
            EQ[c * STR + 32 + d] = (short)f2bf(Qi);
            const float nr = fmaf(Ar, Sr, fmaf(-Ai, Si, Er[i]));
            const float ni = fmaf(Ar, Si, fmaf(Ai, Sr, Ei[i]));
            Sr = nr; Si = ni;
            float nGr, nGi;
            CMUL(nGr, nGi, Ar, Ai, Gr, Gi);
            Gr = nGr; Gi = nGi;
        }
    }
    __syncthreads();                                // b4: Q ready

    // ---- mm3: Y += R x Q ----
    #pragma unroll
    for (int k0 = 0; k0 < 64; k0 += 32) {
        const short8 aR = *(const short8*)&RmB[(m0 + rowi) * 64 + k0 + (quad << 3)];
        #pragma unroll
        for (int nt = 0; nt < 4; ++nt) {
            const short8 bQ = *(const short8*)&EQ[((nt << 4) + rowi) * STR + k0 + (quad << 3)];
            accY[nt] = __builtin_amdgcn_mfma_f32_16x16x32_bf16(aR, bQ, accY[nt], 0, 0, 0);
        }
    }

    // ---- epilogue: += D*u (u from retained Us tile), float4 stores ----
    float* op = out + ((size_t)bh << 12);
    #pragma unroll
    for (int nt = 0; nt < 4; ++nt) {
        const int c    = (nt << 4) + rowi;
        const int toff = m0 + (quad << 2);
        const uint2 uu = *(const uint2*)&Us[c * STR + toff];
        float4 res;
        res.x = fmaf(Dh, bf2f((unsigned short)(uu.x & 0xffffu)), accY[nt][0]);
        res.y = fmaf(Dh, bf2f((unsigned short)(uu.x >> 16)),     accY[nt][1]);
        res.z = fmaf(Dh, bf2f((unsigned short)(uu.y & 0xffffu)), accY[nt][2]);
        res.w = fmaf(Dh, bf2f((unsigned short)(uu.y >> 16)),     accY[nt][3]);
        *(float4*)&op[c * 64 + toff] = res;
    }
}

extern "C" void kernel_launch(void* const* d_in, const int* in_sizes, int n_in,
                              void* d_out, int out_size, void* d_ws, size_t ws_size,
                              hipStream_t stream) {
    const float* u     = (const float*)d_in[0];
    const float* theta = (const float*)d_in[1];
    const float* a     = (const float*)d_in[2];
    const float* Dp    = (const float*)d_in[3];
    const float* b_p   = (const float*)d_in[4];
    const float* c_p   = (const float*)d_in[5];
    const float* x0    = (const float*)d_in[6];
    float* out = (float*)d_out;
    char* ws = (char*)d_ws;
    unsigned short* Hm = (unsigned short*)(ws + WS_H);
    unsigned short* Pm = (unsigned short*)(ws + WS_P);
    unsigned short* Rm = (unsigned short*)(ws + WS_R);
    float4*         C1 = (float4*)(ws + WS_C1);
    float*          C2 = (float*)(ws + WS_C2);

    hipLaunchKernelGGL(s4_pre_kernel, dim3(HH), dim3(256), 0, stream,
                       theta, a, b_p, c_p, x0, Hm, Pm, Rm, C1, C2);
    hipLaunchKernelGGL(s4_main_kernel, dim3(BB * HH), dim3(256), 0, stream,
                       u, Dp, Hm, Pm, Rm, C1, C2, out);
}

// Round 5
// 104.596 us; speedup vs baseline: 1.0052x; 1.0052x over previous
//
#include <hip/hip_runtime.h>

#define BB 8
#define HH 256
#define LL 4096
#define STR 72          // LDS row stride in shorts

// ws byte offsets (~6.2 MB used, rewritten every call)
#define WS_H  0
#define WS_P  (2u*1024*1024)
#define WS_R  (4u*1024*1024)
#define WS_C1 (6u*1024*1024)
#define WS_C2 (6u*1024*1024 + 128u*1024)

typedef __attribute__((ext_vector_type(8))) short short8;   // 8 bf16 = MFMA A/B frag
typedef __attribute__((ext_vector_type(4))) float f32x4;    // MFMA C/D frag

static __device__ inline unsigned short f2bf(float x) {
    union { float f; unsigned u; } v; v.f = x;
    unsigned r = v.u + 0x7fffu + ((v.u >> 16) & 1u);   // RNE
    return (unsigned short)(r >> 16);
}
static __device__ inline float bf2f(unsigned short us) {
    union { unsigned u; float f; } v; v.u = ((unsigned)us) << 16; return v.f;
}

#define CMUL(or_, oi_, ar_, ai_, br_, bi_) do { \
    float _tr = fmaf((ar_), (br_), -(ai_) * (bi_)); \
    float _ti = fmaf((ar_), (bi_), (ai_) * (br_)); \
    (or_) = _tr; (oi_) = _ti; } while (0)

// ---------------- Precompute: one block per h ----------------
__global__ __launch_bounds__(256) void s4_pre_kernel(
    const float* __restrict__ theta, const float* __restrict__ a,
    const float* __restrict__ b_p,   const float* __restrict__ c_p,
    const float* __restrict__ x0,
    unsigned short* __restrict__ Hm, unsigned short* __restrict__ Pm,
    unsigned short* __restrict__ Rm, float4* __restrict__ C1,
    float* __restrict__ C2)
{
    const int tid = threadIdx.x;
    const int h   = blockIdx.x;
    const int d   = tid & 31;
    const int kb  = tid >> 5;
    const float T = 1.0f / (LL - 1);
    __shared__ float h_s[64];

    const float lr = a[h * 32 + d];
    const float li = theta[h * 32 + d];
    float sn, cS;
    sincosf(li * T, &sn, &cS);
    const float er = expf(lr * T);
    const float Rr = er * cS, Ri = er * sn;      // r = exp(ls*T)
    const float den = lr * lr + li * li;
    const float t0r = ((Rr - 1.f) * lr + Ri * li) / den;
    const float t0i = (Ri * lr - (Rr - 1.f) * li) / den;
    const float qq  = b_p[h * 32 + d] * c_p[h * 32 + d];
    const float wre = 2.f * qq * t0r, wim = 2.f * qq * t0i;
    const float vv  = 4.f * T * c_p[h * 32 + d] * x0[h * 32 + d];

    float r2r, r2i, r4r, r4i, r8r, r8i, r16r, r16i, r32r, r32i;
    CMUL(r2r, r2i, Rr, Ri, Rr, Ri);
    CMUL(r4r, r4i, r2r, r2i, r2r, r2i);
    CMUL(r8r, r8i, r4r, r4i, r4r, r4i);
    CMUL(r16r, r16i, r8r, r8i, r8r, r8i);
    CMUL(r32r, r32i, r16r, r16i, r16r, r16i);

    unsigned short* HmB = Hm + h * 4096;
    unsigned short* PmB = Pm + h * 4096;
    unsigned short* RmB = Rm + h * 4096;

    {   // fill Rmat, Pmat, reduce h_k
        float pr = 1.f, pi = 0.f;
        if (kb & 1) CMUL(pr, pi, pr, pi, r8r, r8i);
        if (kb & 2) CMUL(pr, pi, pr, pi, r16r, r16i);
        if (kb & 4) CMUL(pr, pi, pr, pi, r32r, r32i);
        #pragma unroll
        for (int k8 = 0; k8 < 8; ++k8) {
            const int k = (kb << 3) + k8;
            RmB[k * 64 + d]           = f2bf(pr);
            RmB[k * 64 + 32 + d]      = f2bf(-pi);
            PmB[d * 64 + (63 - k)]        = f2bf(pr);
            PmB[(32 + d) * 64 + (63 - k)] = f2bf(pi);
            float hk = fmaf(wre, pr, -wim * pi);     // Re(w * r^k)
            hk += __shfl_xor(hk, 1);
            hk += __shfl_xor(hk, 2);
            hk += __shfl_xor(hk, 4);
            hk += __shfl_xor(hk, 8);
            hk += __shfl_xor(hk, 16);
            if (d == 0) h_s[k] = hk;
            CMUL(pr, pi, pr, pi, Rr, Ri);
        }
    }
    if (tid < 32) {
        float Ar, Ai, wrr, wri;
        CMUL(Ar, Ai, r32r, r32i, r32r, r32i);        // A = r^64
        CMUL(wrr, wri, wre, wim, Rr, Ri);            // w*r
        C1[h * 32 + d] = make_float4(Ar, Ai, wrr, wri);
        C2[h * 32 + d] = vv;
    }
    __syncthreads();

    {   // Toeplitz Hmat[t][tau] = h[t-tau]
        const int t  = tid >> 2;
        const int tb = (tid & 3) << 4;
        #pragma unroll
        for (int g = 0; g < 4; ++g) {
            const int tau0 = tb + (g << 2);
            unsigned short e[4];
            #pragma unroll
            for (int i = 0; i < 4; ++i) {
                const int dt = t - (tau0 + i);
                e[i] = (dt >= 0) ? f2bf(h_s[dt]) : (unsigned short)0;
            }
            uint2 pk;
            pk.x = (unsigned)e[0] | ((unsigned)e[1] << 16);
            pk.y = (unsigned)e[2] | ((unsigned)e[3] << 16);
            *(uint2*)&HmB[t * 64 + tau0] = pk;
        }
    }
}

// ---------------- Main: one block per (h, b-pair); 2 tiles pipelined ----
__global__ __launch_bounds__(256, 4) void s4_main_kernel(
    const float* __restrict__ u, const float* __restrict__ Dp,
    const unsigned short* __restrict__ Hm, const unsigned short* __restrict__ Pm,
    const unsigned short* __restrict__ Rm, const float4* __restrict__ C1,
    const float* __restrict__ C2, float* __restrict__ out)
{
    const int tid = threadIdx.x;
    const int blk = blockIdx.x;           // 1024
    const int hh  = blk >> 2;
    const int bp  = blk & 3;              // handles b = 2bp, 2bp+1

    __shared__ __align__(16) short UsA[64 * STR];
    __shared__ __align__(16) short UsB[64 * STR];
    __shared__ __align__(16) short EQ[64 * STR];
    __shared__ __align__(16) float Seg[32 * 18];

    const int d    = tid & 31;
    const int g    = tid >> 5;
    const int ln   = tid & 63;
    const int m0   = (tid >> 6) << 4;
    const int rowi = ln & 15;
    const int quad = ln >> 4;

    // ---- A-frags for all 3 matmuls -> registers (L2/L3-hot, issued first) ----
    const unsigned short* HmB = Hm + hh * 4096;
    const unsigned short* PmB = Pm + hh * 4096;
    const unsigned short* RmB = Rm + hh * 4096;
    short8 aH[2], aP[2], aR[2];
    #pragma unroll
    for (int kh = 0; kh < 2; ++kh) {
        const int off = (m0 + rowi) * 64 + (kh << 5) + (quad << 3);
        aH[kh] = *(const short8*)&HmB[off];
        aP[kh] = *(const short8*)&PmB[off];
        aR[kh] = *(const short8*)&RmB[off];
    }

    // ---- stage tile0 -> UsA; issue tile1 loads into regs ----
    const float* up0 = u + ((((size_t)(bp * 2) * HH) + hh) << 12);
    const float* up1 = u + ((((size_t)(bp * 2 + 1) * HH) + hh) << 12);
    #pragma unroll
    for (int jj = 0; jj < 4; ++jj) {
        const int v  = tid + (jj << 8);
        const float4 val = ((const float4*)up0)[v];
        const int c  = v >> 4;
        const int t0 = (v & 15) << 2;
        uint2 pk;
        pk.x = (unsigned)f2bf(val.x) | ((unsigned)f2bf(val.y) << 16);
        pk.y = (unsigned)f2bf(val.z) | ((unsigned)f2bf(val.w) << 16);
        *(uint2*)&UsA[c * STR + t0] = pk;
    }
    float4 v1[4];
    #pragma unroll
    for (int jj = 0; jj < 4; ++jj)
        v1[jj] = ((const float4*)up1)[tid + (jj << 8)];

    // ---- constants ----
    const float4 c1 = C1[hh * 32 + d];    // Ar, Ai, wr_r, wr_i
    const float vv  = C2[hh * 32 + d];
    const float Dh  = Dp[hh];
    const float Ar = c1.x, Ai = c1.y;
    float S8r, S8i, S16r, S16i, S32r, S32i;       // A^8, A^16, A^32
    {
        float b1r, b1i, b2r, b2i;
        CMUL(b1r, b1i, Ar, Ai, Ar, Ai);
        CMUL(b2r, b2i, b1r, b1i, b1r, b1i);
        CMUL(S8r, S8i, b2r, b2i, b2r, b2i);
        CMUL(S16r, S16i, S8r, S8i, S8r, S8i);
        CMUL(S32r, S32i, S16r, S16i, S16r, S16i);
    }
    __syncthreads();                               // b1: UsA ready

    #pragma unroll
    for (int it = 0; it < 2; ++it) {
        short* Us = it ? UsB : UsA;

        // ---- mm1 (Y1 = H x U) + mm2 (E = P x U), A-frags from regs ----
        f32x4 accY[4], accE[4];
        #pragma unroll
        for (int nt = 0; nt < 4; ++nt) {
            accY[nt] = (f32x4){0.f, 0.f, 0.f, 0.f};
            accE[nt] = (f32x4){0.f, 0.f, 0.f, 0.f};
        }
        #pragma unroll
        for (int kh = 0; kh < 2; ++kh) {
            const int k0 = kh << 5;
            #pragma unroll
            for (int nt = 0; nt < 4; ++nt) {
                const short8 bU = *(const short8*)&Us[((nt << 4) + rowi) * STR + k0 + (quad << 3)];
                accY[nt] = __builtin_amdgcn_mfma_f32_16x16x32_bf16(aH[kh], bU, accY[nt], 0, 0, 0);
                accE[nt] = __builtin_amdgcn_mfma_f32_16x16x32_bf16(aP[kh], bU, accE[nt], 0, 0, 0);
            }
        }

        // ---- write E planar ----
        #pragma unroll
        for (int nt = 0; nt < 4; ++nt) {
            uint2 pk;
            pk.x = (unsigned)f2bf(accE[nt][0]) | ((unsigned)f2bf(accE[nt][1]) << 16);
            pk.y = (unsigned)f2bf(accE[nt][2]) | ((unsigned)f2bf(accE[nt][3]) << 16);
            *(uint2*)&EQ[((nt << 4) + rowi) * STR + m0 + (quad << 2)] = pk;
        }

        // ---- drain tile1 prefetch into UsB (covered by tile0 compute) ----
        if (it == 0) {
            #pragma unroll
            for (int jj = 0; jj < 4; ++jj) {
                const int v  = tid + (jj << 8);
                const int c  = v >> 4;
                const int t0 = (v & 15) << 2;
                uint2 pk;
                pk.x = (unsigned)f2bf(v1[jj].x) | ((unsigned)f2bf(v1[jj].y) << 16);
                pk.y = (unsigned)f2bf(v1[jj].z) | ((unsigned)f2bf(v1[jj].w) << 16);
                *(uint2*)&UsB[c * STR + t0] = pk;
            }
        }
        __syncthreads();                           // b2: E ready (UsB staged)

        // ---- scan phase a: thread (d,g) owns chunks 8g..8g+7 ----
        const int cb = g << 3;
        float Er[8], Ei[8];
        {
            float Sr = 0.f, Si = 0.f;
            #pragma unroll
            for (int i = 0; i < 8; ++i) {
                const int c = cb + i;
                Er[i] = bf2f((unsigned short)EQ[c * STR + d]);
                Ei[i] = bf2f((unsigned short)EQ[c * STR + 32 + d]);
                const float nr = fmaf(Ar, Sr, fmaf(-Ai, Si, Er[i]));
                const float ni = fmaf(Ar, Si, fmaf(Ai, Sr, Ei[i]));
                Sr = nr; Si = ni;
            }
            Seg[d * 18 + (g << 1)]     = Sr;
            Seg[d * 18 + (g << 1) + 1] = Si;
        }
        __syncthreads();                           // b3: Seg ready

        // ---- scan phase c: combine + emit Q ----
        {
            float offr = 0.f, offi = 0.f;
            #pragma unroll
            for (int gp = 0; gp < 7; ++gp) {
                const float2 sg = *(const float2*)&Seg[d * 18 + (gp << 1)];
                const float nr = fmaf(S8r, offr, fmaf(-S8i, offi, sg.x));
                const float ni = fmaf(S8r, offi, fmaf(S8i, offr, sg.y));
                const bool take = gp < g;
                offr = take ? nr : offr;
                offi = take ? ni : offi;
            }
            float Gr = vv, Gi = 0.f;               // v * A^(8g)
            if (g & 1) { float nr, ni; CMUL(nr, ni, Gr, Gi, S8r, S8i);   Gr = nr; Gi = ni; }
            if (g & 2) { float nr, ni; CMUL(nr, ni, Gr, Gi, S16r, S16i); Gr = nr; Gi = ni; }
            if (g & 4) { float nr, ni; CMUL(nr, ni, Gr, Gi, S32r, S32i); Gr = nr; Gi = ni; }
            const float wrr = c1.z, wri = c1.w;
            float Sr = offr, Si = offi;
            #pragma unroll
            for (int i = 0; i < 8; ++i) {
                const int c = cb + i;
                const float Qr = fmaf(wrr, Sr, fmaf(-wri, Si, Gr));
                const float Qi = fmaf(wrr, Si, fmaf(wri, Sr, Gi));
                EQ[c * STR + d]      = (short)f2bf(Qr);
                EQ[c * STR + 32 + d] = (short)f2bf(Qi);
                const float nr = fmaf(Ar, Sr, fmaf(-Ai, Si, Er[i]));
                const float ni = fmaf(Ar, Si, fmaf(Ai, Sr, Ei[i]));
                Sr = nr; Si = ni;
                float nGr, nGi;
                CMUL(nGr, nGi, Ar, Ai, Gr, Gi);
                Gr = nGr; Gi = nGi;
            }
        }
        __syncthreads();                           // b4: Q ready

        // ---- mm3: Y += R x Q ----
        #pragma unroll
        for (int kh = 0; kh < 2; ++kh) {
            const int k0 = kh << 5;
            #pragma unroll
            for (int nt = 0; nt < 4; ++nt) {
                const short8 bQ = *(const short8*)&EQ[((nt << 4) + rowi) * STR + k0 + (quad << 3)];
                accY[nt] = __builtin_amdgcn_mfma_f32_16x16x32_bf16(aR[kh], bQ, accY[nt], 0, 0, 0);
            }
        }

        // ---- epilogue: += D*u (from LDS tile), float4 stores ----
        float* op = out + ((((size_t)(bp * 2 + it) * HH) + hh) << 12);
        #pragma unroll
        for (int nt = 0; nt < 4; ++nt) {
            const int c    = (nt << 4) + rowi;
            const int toff = m0 + (quad << 2);
            const uint2 uu = *(const uint2*)&Us[c * STR + toff];
            float4 res;
            res.x = fmaf(Dh, bf2f((unsigned short)(uu.x & 0xffffu)), accY[nt][0]);
            res.y = fmaf(Dh, bf2f((unsigned short)(uu.x >> 16)),     accY[nt][1]);
            res.z = fmaf(Dh, bf2f((unsigned short)(uu.y & 0xffffu)), accY[nt][2]);
            res.w = fmaf(Dh, bf2f((unsigned short)(uu.y >> 16)),     accY[nt][3]);
            *(float4*)&op[c * 64 + toff] = res;
        }
        __syncthreads();                           // b5: EQ free for next tile
    }
}

extern "C" void kernel_launch(void* const* d_in, const int* in_sizes, int n_in,
                              void* d_out, int out_size, void* d_ws, size_t ws_size,
                              hipStream_t stream) {
    const float* u     = (const float*)d_in[0];
    const float* theta = (const float*)d_in[1];
    const float* a     = (const float*)d_in[2];
    const float* Dp    = (const float*)d_in[3];
    const float* b_p   = (const float*)d_in[4];
    const float* c_p   = (const float*)d_in[5];
    const float* x0    = (const float*)d_in[6];
    float* out = (float*)d_out;
    char* ws = (char*)d_ws;
    unsigned short* Hm = (unsigned short*)(ws + WS_H);
    unsigned short* Pm = (unsigned short*)(ws + WS_P);
    unsigned short* Rm = (unsigned short*)(ws + WS_R);
    float4*         C1 = (float4*)(ws + WS_C1);
    float*          C2 = (float*)(ws + WS_C2);

    hipLaunchKernelGGL(s4_pre_kernel, dim3(HH), dim3(256), 0, stream,
                       theta, a, b_p, c_p, x0, Hm, Pm, Rm, C1, C2);
    hipLaunchKernelGGL(s4_main_kernel, dim3(HH * 4), dim3(256), 0, stream,
                       u, Dp, Hm, Pm, Rm, C1, C2, out);
}